// Round 1
// baseline (2785.644 us; speedup 1.0000x reference)
//
#include <hip/hip_runtime.h>

#define B_ 4
#define N_ 4096
#define D_ 2048
#define E_ 8
#define R_ 128
#define K_ 1024

// ---------------------------------------------------------------------------
// Kernel 1: gate logits.  One wave (64 lanes) per token; each lane strides D,
// accumulating all E=8 partial dots, then a wave shuffle-reduce.
// Writes logits TRANSPOSED: logitsT[b][e][n]  (contiguous per (b,e) for topk).
// ---------------------------------------------------------------------------
__global__ __launch_bounds__(256) void gate_kernel(const float* __restrict__ x,
                                                   const float* __restrict__ Wg,
                                                   const float* __restrict__ bg,
                                                   float* __restrict__ logitsT) {
  int wave = threadIdx.x >> 6;
  int lane = threadIdx.x & 63;
  int token = blockIdx.x * 4 + wave;   // 0 .. B*N-1
  int b = token / N_;
  int n = token % N_;
  const float* xr = x + (size_t)token * D_;
  float acc[E_];
#pragma unroll
  for (int e = 0; e < E_; ++e) acc[e] = 0.f;
  for (int d = lane; d < D_; d += 64) {
    float xv = xr[d];
    const float* wr = Wg + d * E_;
#pragma unroll
    for (int e = 0; e < E_; ++e) acc[e] += xv * wr[e];
  }
#pragma unroll
  for (int off = 32; off > 0; off >>= 1) {
#pragma unroll
    for (int e = 0; e < E_; ++e) acc[e] += __shfl_down(acc[e], off, 64);
  }
  if (lane == 0) {
#pragma unroll
    for (int e = 0; e < E_; ++e)
      logitsT[((size_t)b * E_ + e) * N_ + n] = acc[e] + bg[e];
  }
}

// ---------------------------------------------------------------------------
// Kernel 2: exact top-K per (b,e) via radix select on monotonic bit keys.
// One block per (b,e); N=4096 keys live in LDS. Ties at the K-th key are
// taken lowest-index-first (matches jax top_k's selected SET).
// ---------------------------------------------------------------------------
__global__ __launch_bounds__(256) void topk_kernel(const float* __restrict__ logitsT,
                                                   int* __restrict__ I,
                                                   float* __restrict__ G) {
  __shared__ unsigned keys[N_];
  __shared__ float vals[N_];
  __shared__ unsigned s_cnt;
  int be = blockIdx.x;
  const float* lg = logitsT + (size_t)be * N_;
  int tid = threadIdx.x;
  for (int n = tid; n < N_; n += 256) {
    float v = lg[n];
    unsigned u = __float_as_uint(v);
    keys[n] = (u & 0x80000000u) ? ~u : (u | 0x80000000u);  // larger float -> larger key
    vals[n] = v;
  }
  __syncthreads();

  unsigned prefix = 0;
  int rem = K_;  // rank of target within current prefix-matching subset
  for (int bit = 31; bit >= 0; --bit) {
    if (tid == 0) s_cnt = 0;
    __syncthreads();
    unsigned hi_mask = (bit == 31) ? 0u : (0xFFFFFFFFu << (bit + 1));
    unsigned sel_mask = hi_mask | (1u << bit);
    unsigned want = prefix | (1u << bit);
    unsigned lc = 0;
    for (int n = tid; n < N_; n += 256)
      lc += ((keys[n] & sel_mask) == want) ? 1u : 0u;
    atomicAdd(&s_cnt, lc);
    __syncthreads();
    unsigned c = s_cnt;
    if ((int)c >= rem) prefix = want;
    else rem -= (int)c;
    __syncthreads();
  }
  unsigned kth = prefix;  // exact key value of the K-th largest

  if (tid == 0) s_cnt = 0;
  __syncthreads();
  int* Ibe = I + (size_t)be * K_;
  float* Gbe = G + (size_t)be * K_;
  for (int n = tid; n < N_; n += 256) {
    if (keys[n] > kth) {
      unsigned p = atomicAdd(&s_cnt, 1u);
      Ibe[p] = n;
      Gbe[p] = vals[n];
    }
  }
  __syncthreads();
  if (tid == 0) {
    unsigned p = s_cnt;  // == K_ - rem
    for (int n = 0; n < N_ && (int)p < K_; ++n) {
      if (keys[n] == kth) { Ibe[p] = n; Gbe[p] = vals[n]; ++p; }
    }
  }
}

// ---------------------------------------------------------------------------
// Kernel 3: out = residual  (scatter target init), vectorized.
// ---------------------------------------------------------------------------
__global__ __launch_bounds__(256) void init_out_kernel(const float4* __restrict__ res,
                                                       float4* __restrict__ out, int n4) {
  int i = blockIdx.x * blockDim.x + threadIdx.x;
  if (i < n4) out[i] = res[i];
}

// ---------------------------------------------------------------------------
// Kernel 4: down-proj. Per (b,e): [K=1024 gathered tokens x D=2048] x Wd[e]
// [2048 x 128] -> h [1024 x 128], +bd, relu.
// Tile: BM=64 tokens, BN=128 (full R), BK=16; 256 threads, 4x8 accum/thread.
// ---------------------------------------------------------------------------
__global__ __launch_bounds__(256) void down_kernel(const float* __restrict__ x,
                                                   const float* __restrict__ Wd,
                                                   const float* __restrict__ bd,
                                                   const int* __restrict__ I,
                                                   float* __restrict__ h) {
  __shared__ float As[64][17];
  __shared__ float Bs[16][128];
  __shared__ int s_tok[64];
  int be = blockIdx.x;  // b*E + e
  int m0 = blockIdx.y * 64;
  int b = be / E_, e = be % E_;
  int tid = threadIdx.x;
  const int* Ibe = I + (size_t)be * K_;
  if (tid < 64) s_tok[tid] = Ibe[m0 + tid];
  __syncthreads();
  int tcol = tid & 15;   // -> cols 8*tcol .. 8*tcol+7
  int trow = tid >> 4;   // -> rows 4*trow .. 4*trow+3
  float acc[4][8] = {};
  const float* Wde = Wd + (size_t)e * D_ * R_;
  for (int d0 = 0; d0 < D_; d0 += 16) {
#pragma unroll
    for (int i = 0; i < 4; ++i) {
      int lin = tid + 256 * i;
      int row = lin >> 4, kk = lin & 15;
      As[row][kk] = x[((size_t)b * N_ + s_tok[row]) * D_ + d0 + kk];
    }
#pragma unroll
    for (int i = 0; i < 8; ++i) {
      int lin = tid + 256 * i;
      int kk = lin >> 7, c = lin & 127;
      Bs[kk][c] = Wde[(size_t)(d0 + kk) * R_ + c];
    }
    __syncthreads();
#pragma unroll
    for (int kk = 0; kk < 16; ++kk) {
      float a[4], bv[8];
#pragma unroll
      for (int i = 0; i < 4; ++i) a[i] = As[trow * 4 + i][kk];
#pragma unroll
      for (int j = 0; j < 8; ++j) bv[j] = Bs[kk][tcol * 8 + j];
#pragma unroll
      for (int i = 0; i < 4; ++i)
#pragma unroll
        for (int j = 0; j < 8; ++j) acc[i][j] += a[i] * bv[j];
    }
    __syncthreads();
  }
#pragma unroll
  for (int i = 0; i < 4; ++i) {
    int kidx = m0 + trow * 4 + i;
#pragma unroll
    for (int j = 0; j < 8; ++j) {
      int r = tcol * 8 + j;
      float v = acc[i][j] + bd[e * R_ + r];
      h[((size_t)be * K_ + kidx) * R_ + r] = v > 0.f ? v : 0.f;
    }
  }
}

// ---------------------------------------------------------------------------
// Kernel 5: up-proj + weighted scatter-add.
// Per block: (b,e), 64-token tile, 128-column chunk of D. K-dim = R = 128.
// epilogue: atomicAdd( out[b, tok, c], G * (acc + bu + x[b,tok,c]) ).
// ---------------------------------------------------------------------------
__global__ __launch_bounds__(256) void up_kernel(const float* __restrict__ x,
                                                 const float* __restrict__ Wu,
                                                 const float* __restrict__ bu,
                                                 const int* __restrict__ I,
                                                 const float* __restrict__ G,
                                                 const float* __restrict__ h,
                                                 float* __restrict__ out) {
  __shared__ float As[64][17];
  __shared__ float Bs[16][128];
  __shared__ int s_tok[64];
  __shared__ float s_g[64];
  int bid = blockIdx.x;
  int nchunk = bid & 15;         // D/128 = 16
  int mtile = (bid >> 4) & 15;   // K/64  = 16
  int be = bid >> 8;             // B*E   = 32
  int b = be / E_, e = be % E_;
  int m0 = mtile * 64;
  int n0 = nchunk * 128;
  int tid = threadIdx.x;
  const int* Ibe = I + (size_t)be * K_;
  const float* Gbe = G + (size_t)be * K_;
  if (tid < 64) { s_tok[tid] = Ibe[m0 + tid]; s_g[tid] = Gbe[m0 + tid]; }
  __syncthreads();
  int tcol = tid & 15, trow = tid >> 4;
  float acc[4][8] = {};
  const float* Wue = Wu + (size_t)e * R_ * D_;
  const float* hbe = h + ((size_t)be * K_ + m0) * R_;
  for (int k0 = 0; k0 < R_; k0 += 16) {
#pragma unroll
    for (int i = 0; i < 4; ++i) {
      int lin = tid + 256 * i;
      int row = lin >> 4, kk = lin & 15;
      As[row][kk] = hbe[(size_t)row * R_ + k0 + kk];
    }
#pragma unroll
    for (int i = 0; i < 8; ++i) {
      int lin = tid + 256 * i;
      int kk = lin >> 7, c = lin & 127;
      Bs[kk][c] = Wue[(size_t)(k0 + kk) * D_ + n0 + c];
    }
    __syncthreads();
#pragma unroll
    for (int kk = 0; kk < 16; ++kk) {
      float a[4], bv[8];
#pragma unroll
      for (int i = 0; i < 4; ++i) a[i] = As[trow * 4 + i][kk];
#pragma unroll
      for (int j = 0; j < 8; ++j) bv[j] = Bs[kk][tcol * 8 + j];
#pragma unroll
      for (int i = 0; i < 4; ++i)
#pragma unroll
        for (int j = 0; j < 8; ++j) acc[i][j] += a[i] * bv[j];
    }
    __syncthreads();
  }
#pragma unroll
  for (int i = 0; i < 4; ++i) {
    int row = trow * 4 + i;
    int tok = s_tok[row];
    float g = s_g[row];
    const float* xr = x + ((size_t)b * N_ + tok) * D_ + n0;
    float* outr = out + ((size_t)b * N_ + tok) * D_ + n0;
#pragma unroll
    for (int j = 0; j < 8; ++j) {
      int c = tcol * 8 + j;
      float v = (acc[i][j] + bu[(size_t)e * D_ + n0 + c] + xr[c]) * g;
      atomicAdd(&outr[c], v);
    }
  }
}

// ---------------------------------------------------------------------------
extern "C" void kernel_launch(void* const* d_in, const int* in_sizes, int n_in,
                              void* d_out, int out_size, void* d_ws, size_t ws_size,
                              hipStream_t stream) {
  const float* x        = (const float*)d_in[0];
  const float* residual = (const float*)d_in[1];
  const float* Wg       = (const float*)d_in[2];
  const float* bg       = (const float*)d_in[3];
  const float* Wd       = (const float*)d_in[4];
  const float* bd       = (const float*)d_in[5];
  const float* Wu       = (const float*)d_in[6];
  const float* bu       = (const float*)d_in[7];
  float* out = (float*)d_out;

  // workspace layout (floats): logitsT | I | G | h   (~16.8 MB total)
  float* wsf = (float*)d_ws;
  float* logitsT = wsf;
  int*   Ibuf    = (int*)(wsf + (size_t)B_ * E_ * N_);
  float* Gbuf    = wsf + (size_t)B_ * E_ * N_ + (size_t)B_ * E_ * K_;
  float* hbuf    = Gbuf + (size_t)B_ * E_ * K_;

  gate_kernel<<<B_ * N_ / 4, 256, 0, stream>>>(x, Wg, bg, logitsT);
  topk_kernel<<<B_ * E_, 256, 0, stream>>>(logitsT, Ibuf, Gbuf);
  init_out_kernel<<<(B_ * N_ * D_ / 4 + 255) / 256, 256, 0, stream>>>(
      (const float4*)residual, (float4*)out, B_ * N_ * D_ / 4);
  down_kernel<<<dim3(B_ * E_, K_ / 64), 256, 0, stream>>>(x, Wd, bd, Ibuf, hbuf);
  up_kernel<<<B_ * E_ * (K_ / 64) * (D_ / 128), 256, 0, stream>>>(
      x, Wu, bu, Ibuf, Gbuf, hbuf, out);
}

// Round 2
// 728.573 us; speedup vs baseline: 3.8234x; 3.8234x over previous
//
#include <hip/hip_runtime.h>

#define B_ 4
#define N_ 4096
#define D_ 2048
#define E_ 8
#define R_ 128
#define K_ 1024

typedef __attribute__((ext_vector_type(8))) short bf16x8;
typedef __attribute__((ext_vector_type(4))) float f32x4;

__device__ inline unsigned short f2bf(float f) {
  unsigned u = __float_as_uint(f);
  unsigned r = (u + 0x7FFFu + ((u >> 16) & 1u)) >> 16;  // RNE
  return (unsigned short)r;
}

// ---------------------------------------------------------------------------
// Gate logits (fp32 — top-k boundary gaps ~1e-3 require fp32 precision here).
// One wave per token, lanes stride D. Writes logitsT[b][e][n].
// ---------------------------------------------------------------------------
__global__ __launch_bounds__(256) void gate_kernel(const float* __restrict__ x,
                                                   const float* __restrict__ Wg,
                                                   const float* __restrict__ bg,
                                                   float* __restrict__ logitsT) {
  int wave = threadIdx.x >> 6;
  int lane = threadIdx.x & 63;
  int token = blockIdx.x * 4 + wave;
  int b = token / N_;
  int n = token % N_;
  const float* xr = x + (size_t)token * D_;
  float acc[E_];
#pragma unroll
  for (int e = 0; e < E_; ++e) acc[e] = 0.f;
  for (int d = lane; d < D_; d += 64) {
    float xv = xr[d];
    const float* wr = Wg + d * E_;
#pragma unroll
    for (int e = 0; e < E_; ++e) acc[e] += xv * wr[e];
  }
#pragma unroll
  for (int off = 32; off > 0; off >>= 1) {
#pragma unroll
    for (int e = 0; e < E_; ++e) acc[e] += __shfl_down(acc[e], off, 64);
  }
  if (lane == 0) {
#pragma unroll
    for (int e = 0; e < E_; ++e)
      logitsT[((size_t)b * E_ + e) * N_ + n] = acc[e] + bg[e];
  }
}

// ---------------------------------------------------------------------------
// Exact top-K per (b,e): radix select on monotonic keys; ties lowest-index
// first via parallel rank (replaces round-1's serial tid-0 scan).
// ---------------------------------------------------------------------------
__global__ __launch_bounds__(256) void topk_kernel(const float* __restrict__ logitsT,
                                                   int* __restrict__ I,
                                                   float* __restrict__ G) {
  __shared__ unsigned keys[N_];
  __shared__ float vals[N_];
  __shared__ int s_tie[N_];
  __shared__ unsigned s_cnt;
  int be = blockIdx.x;
  const float* lg = logitsT + (size_t)be * N_;
  int tid = threadIdx.x;
  for (int n = tid; n < N_; n += 256) {
    float v = lg[n];
    unsigned u = __float_as_uint(v);
    keys[n] = (u & 0x80000000u) ? ~u : (u | 0x80000000u);
    vals[n] = v;
  }
  __syncthreads();

  unsigned prefix = 0;
  int rem = K_;
  for (int bit = 31; bit >= 0; --bit) {
    if (tid == 0) s_cnt = 0;
    __syncthreads();
    unsigned hi_mask = (bit == 31) ? 0u : (0xFFFFFFFFu << (bit + 1));
    unsigned sel_mask = hi_mask | (1u << bit);
    unsigned want = prefix | (1u << bit);
    unsigned lc = 0;
    for (int n = tid; n < N_; n += 256)
      lc += ((keys[n] & sel_mask) == want) ? 1u : 0u;
    atomicAdd(&s_cnt, lc);
    __syncthreads();
    unsigned c = s_cnt;
    if ((int)c >= rem) prefix = want;
    else rem -= (int)c;
    __syncthreads();
  }
  unsigned kth = prefix;

  if (tid == 0) s_cnt = 0;
  __syncthreads();
  int* Ibe = I + (size_t)be * K_;
  float* Gbe = G + (size_t)be * K_;
  for (int n = tid; n < N_; n += 256) {
    if (keys[n] > kth) {
      unsigned p = atomicAdd(&s_cnt, 1u);
      Ibe[p] = n;
      Gbe[p] = vals[n];
    }
  }
  __syncthreads();
  if (tid == 0) s_cnt = 0;  // reuse as tie counter; strict-greater count == K_-rem
  __syncthreads();
  for (int n = tid; n < N_; n += 256)
    if (keys[n] == kth) s_tie[atomicAdd(&s_cnt, 1u)] = n;
  __syncthreads();
  int t = (int)s_cnt;
  int base = K_ - rem;
  for (int i = tid; i < t; i += 256) {
    int n = s_tie[i];
    int rank = 0;
    for (int j = 0; j < t; ++j) rank += (s_tie[j] < n) ? 1 : 0;
    if (rank < rem) { Ibe[base + rank] = n; Gbe[base + rank] = vals[n]; }
  }
}

// ---------------------------------------------------------------------------
// Pre-passes: x -> bf16; Wd -> WdT[e][r][d] bf16; Wu -> WuT[e][d][r] bf16.
// ---------------------------------------------------------------------------
__global__ __launch_bounds__(256) void cvt_x_kernel(const float4* __restrict__ xin,
                                                    ushort4* __restrict__ xbf, int n4) {
  int i = blockIdx.x * 256 + threadIdx.x;
  if (i >= n4) return;
  float4 v = xin[i];
  ushort4 o;
  o.x = f2bf(v.x); o.y = f2bf(v.y); o.z = f2bf(v.z); o.w = f2bf(v.w);
  xbf[i] = o;
}

__global__ __launch_bounds__(256) void cvt_wd_kernel(const float* __restrict__ Wd,
                                                     unsigned short* __restrict__ WdT) {
  int t = blockIdx.x * 256 + threadIdx.x;      // [e][r][d]
  int d = t & (D_ - 1);
  int r = (t >> 11) & (R_ - 1);
  int e = t >> 18;
  WdT[t] = f2bf(Wd[((size_t)e * D_ + d) * R_ + r]);
}

__global__ __launch_bounds__(256) void cvt_wu_kernel(const float* __restrict__ Wu,
                                                     unsigned short* __restrict__ WuT) {
  int t = blockIdx.x * 256 + threadIdx.x;      // [e][d][r]
  int r = t & (R_ - 1);
  int d = (t >> 7) & (D_ - 1);
  int e = t >> 18;
  WuT[t] = f2bf(Wu[((size_t)e * R_ + r) * D_ + d]);
}

__global__ __launch_bounds__(256) void init_out_kernel(const float4* __restrict__ res,
                                                       float4* __restrict__ out, int n4) {
  int i = blockIdx.x * blockDim.x + threadIdx.x;
  if (i < n4) out[i] = res[i];
}

// ---------------------------------------------------------------------------
// Down: per (b,e) gathered [1024 x 2048] @ WdT^T -> h[1024 x 128], relu, bf16.
// Block: 64x128 tile, BK=64, 4 waves of 32x64. MFMA 16x16x32 bf16.
// LDS stride 72 elems (144 B): 16B-aligned, 2-way bank alias (free).
// ---------------------------------------------------------------------------
__global__ __launch_bounds__(256) void down_mfma(const unsigned short* __restrict__ xbf,
                                                 const unsigned short* __restrict__ WdT,
                                                 const float* __restrict__ bd,
                                                 const int* __restrict__ I,
                                                 unsigned short* __restrict__ h) {
  __shared__ unsigned short As[64 * 72] __attribute__((aligned(16)));
  __shared__ unsigned short Bs[128 * 72] __attribute__((aligned(16)));
  __shared__ int s_tok[64];
  int be = blockIdx.x;
  int m0 = blockIdx.y * 64;
  int b = be >> 3, e = be & 7;
  int tid = threadIdx.x;
  if (tid < 64) s_tok[tid] = I[be * K_ + m0 + tid];
  __syncthreads();
  int lane = tid & 63, wave = tid >> 6;
  int l15 = lane & 15, quad = lane >> 4;
  int wrow = (wave >> 1) * 32, wcol = (wave & 1) * 64;

  // hoist gathered-row base pointers (2 A-granules, 4 B-granules per thread)
  const unsigned short* srcA[2];
  int dstA[2];
#pragma unroll
  for (int i = 0; i < 2; ++i) {
    int g = tid + 256 * i;
    int row = g >> 3, part = g & 7;
    srcA[i] = xbf + ((size_t)(b * N_ + s_tok[row])) * D_ + part * 8;
    dstA[i] = row * 72 + part * 8;
  }
  const unsigned short* Wde = WdT + (size_t)e * R_ * D_;
  const unsigned short* srcB[4];
  int dstB[4];
#pragma unroll
  for (int i = 0; i < 4; ++i) {
    int g = tid + 256 * i;
    int row = g >> 3, part = g & 7;
    srcB[i] = Wde + (size_t)row * D_ + part * 8;
    dstB[i] = row * 72 + part * 8;
  }

  f32x4 zv = {0.f, 0.f, 0.f, 0.f};
  f32x4 acc[2][4];
#pragma unroll
  for (int mi = 0; mi < 2; ++mi)
#pragma unroll
    for (int ni = 0; ni < 4; ++ni) acc[mi][ni] = zv;

  for (int d0 = 0; d0 < D_; d0 += 64) {
#pragma unroll
    for (int i = 0; i < 2; ++i)
      *(uint4*)&As[dstA[i]] = *(const uint4*)(srcA[i] + d0);
#pragma unroll
    for (int i = 0; i < 4; ++i)
      *(uint4*)&Bs[dstB[i]] = *(const uint4*)(srcB[i] + d0);
    __syncthreads();
#pragma unroll
    for (int ks = 0; ks < 64; ks += 32) {
      bf16x8 a[2], bb[4];
#pragma unroll
      for (int mi = 0; mi < 2; ++mi)
        a[mi] = *(const bf16x8*)&As[(wrow + mi * 16 + l15) * 72 + ks + quad * 8];
#pragma unroll
      for (int ni = 0; ni < 4; ++ni)
        bb[ni] = *(const bf16x8*)&Bs[(wcol + ni * 16 + l15) * 72 + ks + quad * 8];
#pragma unroll
      for (int mi = 0; mi < 2; ++mi)
#pragma unroll
        for (int ni = 0; ni < 4; ++ni)
          acc[mi][ni] = __builtin_amdgcn_mfma_f32_16x16x32_bf16(a[mi], bb[ni], acc[mi][ni], 0, 0, 0);
    }
    __syncthreads();
  }
#pragma unroll
  for (int mi = 0; mi < 2; ++mi) {
#pragma unroll
    for (int ni = 0; ni < 4; ++ni) {
      int col = wcol + ni * 16 + l15;
      float bias = bd[e * R_ + col];
#pragma unroll
      for (int r = 0; r < 4; ++r) {
        int mrow = m0 + wrow + mi * 16 + quad * 4 + r;
        float v = acc[mi][ni][r] + bias;
        h[((size_t)be * K_ + mrow) * R_ + col] = f2bf(v > 0.f ? v : 0.f);
      }
    }
  }
}

// ---------------------------------------------------------------------------
// Up (one expert per launch => top-K tokens distinct => atomic-free RMW):
// h[128 x 128] @ WuT^T chunk -> out[b,tok,n0+c] += g*(acc + bu + x).
// Block: 128x128, K=R=128 single stage, 4 waves of 64x64.
// LDS stride 136 elems (272 B): 16B-aligned, 2-way bank alias.
// ---------------------------------------------------------------------------
__global__ __launch_bounds__(256) void up_mfma(const float* __restrict__ x,
                                               const unsigned short* __restrict__ WuT,
                                               const float* __restrict__ bu,
                                               const int* __restrict__ I,
                                               const float* __restrict__ G,
                                               const unsigned short* __restrict__ h,
                                               float* __restrict__ out, int e) {
  __shared__ unsigned short As[128 * 136] __attribute__((aligned(16)));
  __shared__ unsigned short Bs[128 * 136] __attribute__((aligned(16)));
  __shared__ int s_tok[128];
  __shared__ float s_g[128];
  int ntile = blockIdx.x;   // 16
  int mtile = blockIdx.y;   // 8
  int b = blockIdx.z;       // 4
  int be = b * E_ + e;
  int m0 = mtile * 128, n0 = ntile * 128;
  int tid = threadIdx.x;
  if (tid < 128) {
    s_tok[tid] = I[be * K_ + m0 + tid];
    s_g[tid] = G[be * K_ + m0 + tid];
  }
  const unsigned short* hbe = h + ((size_t)be * K_ + m0) * R_;
  const unsigned short* Wue = WuT + ((size_t)e * D_ + n0) * R_;
#pragma unroll
  for (int i = 0; i < 8; ++i) {
    int g = tid + 256 * i;
    int row = g >> 4, part = g & 15;
    *(uint4*)&As[row * 136 + part * 8] = *(const uint4*)(hbe + (size_t)row * R_ + part * 8);
  }
#pragma unroll
  for (int i = 0; i < 8; ++i) {
    int g = tid + 256 * i;
    int row = g >> 4, part = g & 15;
    *(uint4*)&Bs[row * 136 + part * 8] = *(const uint4*)(Wue + (size_t)row * R_ + part * 8);
  }
  __syncthreads();

  int lane = tid & 63, wave = tid >> 6;
  int l15 = lane & 15, quad = lane >> 4;
  int wrow = (wave >> 1) * 64, wcol = (wave & 1) * 64;
  f32x4 zv = {0.f, 0.f, 0.f, 0.f};
  f32x4 acc[4][4];
#pragma unroll
  for (int mi = 0; mi < 4; ++mi)
#pragma unroll
    for (int ni = 0; ni < 4; ++ni) acc[mi][ni] = zv;

#pragma unroll
  for (int ks = 0; ks < 128; ks += 32) {
    bf16x8 a[4], bb[4];
#pragma unroll
    for (int mi = 0; mi < 4; ++mi)
      a[mi] = *(const bf16x8*)&As[(wrow + mi * 16 + l15) * 136 + ks + quad * 8];
#pragma unroll
    for (int ni = 0; ni < 4; ++ni)
      bb[ni] = *(const bf16x8*)&Bs[(wcol + ni * 16 + l15) * 136 + ks + quad * 8];
#pragma unroll
    for (int mi = 0; mi < 4; ++mi)
#pragma unroll
      for (int ni = 0; ni < 4; ++ni)
        acc[mi][ni] = __builtin_amdgcn_mfma_f32_16x16x32_bf16(a[mi], bb[ni], acc[mi][ni], 0, 0, 0);
  }

#pragma unroll
  for (int mi = 0; mi < 4; ++mi) {
#pragma unroll
    for (int r = 0; r < 4; ++r) {
      int row = wrow + mi * 16 + quad * 4 + r;
      int tok = s_tok[row];
      float g = s_g[row];
      const float* xr = x + ((size_t)(b * N_ + tok)) * D_ + n0;
      float* outr = out + ((size_t)(b * N_ + tok)) * D_ + n0;
#pragma unroll
      for (int ni = 0; ni < 4; ++ni) {
        int col = wcol + ni * 16 + l15;
        float v = g * (acc[mi][ni][r] + bu[e * D_ + n0 + col] + xr[col]);
        outr[col] += v;  // race-free: tokens distinct within (b,e); experts serialized by launch
      }
    }
  }
}

// ---------------------------------------------------------------------------
extern "C" void kernel_launch(void* const* d_in, const int* in_sizes, int n_in,
                              void* d_out, int out_size, void* d_ws, size_t ws_size,
                              hipStream_t stream) {
  const float* x        = (const float*)d_in[0];
  const float* residual = (const float*)d_in[1];
  const float* Wg       = (const float*)d_in[2];
  const float* bg       = (const float*)d_in[3];
  const float* Wd       = (const float*)d_in[4];
  const float* bd       = (const float*)d_in[5];
  const float* Wu       = (const float*)d_in[6];
  const float* bu       = (const float*)d_in[7];
  float* out = (float*)d_out;

  // ws layout (all region sizes 256B-multiples):
  // logitsT f32[B*E*N] | I i32[B*E*K] | G f32[B*E*K] | xbf bf16[B*N*D]
  // | WdT bf16[E*R*D] | WuT bf16[E*D*R] | h bf16[B*E*K*R]     (~85 MB)
  char* p = (char*)d_ws;
  float* logitsT = (float*)p;            p += (size_t)B_ * E_ * N_ * 4;
  int* Ibuf = (int*)p;                   p += (size_t)B_ * E_ * K_ * 4;
  float* Gbuf = (float*)p;               p += (size_t)B_ * E_ * K_ * 4;
  unsigned short* xbf = (unsigned short*)p;  p += (size_t)B_ * N_ * D_ * 2;
  unsigned short* WdT = (unsigned short*)p;  p += (size_t)E_ * R_ * D_ * 2;
  unsigned short* WuT = (unsigned short*)p;  p += (size_t)E_ * D_ * R_ * 2;
  unsigned short* hbuf = (unsigned short*)p;

  gate_kernel<<<B_ * N_ / 4, 256, 0, stream>>>(x, Wg, bg, logitsT);
  topk_kernel<<<B_ * E_, 256, 0, stream>>>(logitsT, Ibuf, Gbuf);
  cvt_x_kernel<<<(B_ * N_ * D_ / 4 + 255) / 256, 256, 0, stream>>>(
      (const float4*)x, (ushort4*)xbf, B_ * N_ * D_ / 4);
  cvt_wd_kernel<<<E_ * D_ * R_ / 256, 256, 0, stream>>>(Wd, WdT);
  cvt_wu_kernel<<<E_ * D_ * R_ / 256, 256, 0, stream>>>(Wu, WuT);
  init_out_kernel<<<B_ * N_ * D_ / 4 / 256, 256, 0, stream>>>(
      (const float4*)residual, (float4*)out, B_ * N_ * D_ / 4);
  down_mfma<<<dim3(B_ * E_, K_ / 64), 256, 0, stream>>>(xbf, WdT, bd, Ibuf, hbuf);
  for (int e = 0; e < E_; ++e)
    up_mfma<<<dim3(D_ / 128, K_ / 128, B_), 256, 0, stream>>>(
        x, WuT, bu, Ibuf, Gbuf, hbuf, out, e);
}